// Round 4
// baseline (744.727 us; speedup 1.0000x reference)
//
#include <hip/hip_runtime.h>
#include <math.h>

// ---------------------------------------------------------------------------
// TacticalGAT round 4: fused GAT kernels with loop-invariant weights hoisted
// to registers (was: 16 ds_read_b128 of constants per batch -> LDS-pipe bound),
// channel-pair phase B (b64 rows, shared exp), srcs/ea prefetch, cheaper
// epilogue reductions.  Wl/Wr GEMMs fused per layer (X staged once).
// ---------------------------------------------------------------------------

__device__ __forceinline__ void wbar() { __builtin_amdgcn_wave_barrier(); }

// ---------------- CSR build -------------------------------------------------
__global__ void hist_k(const int* __restrict__ dst, int* __restrict__ deg, int E) {
  int e = blockIdx.x * 256 + threadIdx.x;
  if (e < E) atomicAdd(&deg[dst[e]], 1);
}

__global__ void blocksum_k(const int* __restrict__ deg, int* __restrict__ bsum, int N) {
  __shared__ int s[256];
  int i = blockIdx.x * 256 + threadIdx.x;
  s[threadIdx.x] = (i < N) ? deg[i] : 0;
  __syncthreads();
  for (int off = 128; off; off >>= 1) {
    if (threadIdx.x < off) s[threadIdx.x] += s[threadIdx.x + off];
    __syncthreads();
  }
  if (threadIdx.x == 0) bsum[blockIdx.x] = s[0];
}

__global__ void scan_bsum_k(int* __restrict__ bsum, int nb) {
  __shared__ int s[256];
  int t = threadIdx.x;
  s[t] = (t < nb) ? bsum[t] : 0;
  __syncthreads();
  for (int off = 1; off < 256; off <<= 1) {
    int v = (t >= off) ? s[t - off] : 0;
    __syncthreads();
    if (t >= off) s[t] += v;
    __syncthreads();
  }
  int excl = (t == 0) ? 0 : s[t - 1];
  if (t < nb) bsum[t] = excl;
}

__global__ void writeptr_k(const int* __restrict__ deg, const int* __restrict__ bsum,
                           int* __restrict__ rowptr, int* __restrict__ cursor, int N, int E) {
  __shared__ int s[256];
  int t = threadIdx.x;
  int i = blockIdx.x * 256 + t;
  s[t] = (i < N) ? deg[i] : 0;
  __syncthreads();
  for (int off = 1; off < 256; off <<= 1) {
    int v = (t >= off) ? s[t - off] : 0;
    __syncthreads();
    if (t >= off) s[t] += v;
    __syncthreads();
  }
  int excl = bsum[blockIdx.x] + ((t == 0) ? 0 : s[t - 1]);
  if (i < N) {
    rowptr[i] = excl;
    cursor[i] = excl;
  }
  if (i == N - 1) rowptr[N] = E;
}

__global__ void fill_k(const int* __restrict__ src, const int* __restrict__ dst,
                       const float* __restrict__ eattr, int* __restrict__ cursor,
                       int* __restrict__ srcs_s, float4* __restrict__ ea4, int E) {
  int e = blockIdx.x * 256 + threadIdx.x;
  if (e >= E) return;
  int d = dst[e];
  int pos = atomicAdd(&cursor[d], 1);
  srcs_s[pos] = src[e];
  ea4[pos] = make_float4(eattr[e * 3 + 0], eattr[e * 3 + 1], eattr[e * 3 + 2], 0.0f);
}

// ---------------- fused dual node linear (Wl & Wr share X reads) ------------
// out{1,2}[n,j] = sum_k X[n,k]*W{1,2}[j,k] + b{1,2}[j], K=128.
template <int J, int RB>
__global__ __launch_bounds__(256) void node_linear2_k(
    const float* __restrict__ X,
    const float* __restrict__ W1, const float* __restrict__ b1v,
    const float* __restrict__ W2, const float* __restrict__ b2v,
    float* __restrict__ out1, float* __restrict__ out2, int nrows) {
  constexpr int K = 128, KB = 32;
  constexpr int JG = J / 4;
  static_assert((JG * (RB / 4)) == 256, "tile mismatch");
  __shared__ __align__(16) float sW1[KB][J];
  __shared__ __align__(16) float sW2[KB][J];
  __shared__ float sX[RB][K + 1];

  int n0 = blockIdx.x * RB;
  for (int idx = threadIdx.x; idx < RB * K; idx += 256) {
    int rr = idx >> 7, k = idx & 127;
    int n = n0 + rr;
    sX[rr][k] = (n < nrows) ? X[(size_t)n * K + k] : 0.0f;
  }
  int jg = threadIdx.x % JG;
  int rg = threadIdx.x / JG;

  float acc1[4][4] = {}, acc2[4][4] = {};
  for (int kb = 0; kb < 4; ++kb) {
    __syncthreads();
    for (int idx = threadIdx.x; idx < KB * J; idx += 256) {
      int j = idx % J, k = idx / J;
      sW1[k][j] = W1[j * K + kb * KB + k];
      sW2[k][j] = W2[j * K + kb * KB + k];
    }
    __syncthreads();
#pragma unroll
    for (int k = 0; k < KB; ++k) {
      float4 wa = *(const float4*)&sW1[k][jg * 4];
      float4 wb = *(const float4*)&sW2[k][jg * 4];
#pragma unroll
      for (int i = 0; i < 4; ++i) {
        float xv = sX[rg * 4 + i][kb * KB + k];
        acc1[i][0] += xv * wa.x; acc1[i][1] += xv * wa.y;
        acc1[i][2] += xv * wa.z; acc1[i][3] += xv * wa.w;
        acc2[i][0] += xv * wb.x; acc2[i][1] += xv * wb.y;
        acc2[i][2] += xv * wb.z; acc2[i][3] += xv * wb.w;
      }
    }
  }
  float4 bv1 = *(const float4*)&b1v[jg * 4];
  float4 bv2 = *(const float4*)&b2v[jg * 4];
#pragma unroll
  for (int i = 0; i < 4; ++i) {
    int n = n0 + rg * 4 + i;
    if (n < nrows) {
      float4 o1 = make_float4(acc1[i][0] + bv1.x, acc1[i][1] + bv1.y,
                              acc1[i][2] + bv1.z, acc1[i][3] + bv1.w);
      float4 o2 = make_float4(acc2[i][0] + bv2.x, acc2[i][1] + bv2.y,
                              acc2[i][2] + bv2.z, acc2[i][3] + bv2.w);
      *(float4*)&out1[(size_t)n * J + jg * 4] = o1;
      *(float4*)&out2[(size_t)n * J + jg * 4] = o2;
    }
  }
}

// ---------------- fused GATv2 layer 1 (H=4, C=32, concat, 128 out) ----------
// one wave per node; 8-edge batches; weights/att/xr-chunk in registers.
__global__ __launch_bounds__(256, 4) void gat1_fused_k(
    const int* __restrict__ rowptr, const int* __restrict__ srcs,
    const float4* __restrict__ ea4, const float* __restrict__ xl,
    const float* __restrict__ xr, const float* __restrict__ We,
    const float* __restrict__ att, const float* __restrict__ bias,
    float* __restrict__ out, int N) {
  __shared__ __align__(16) float lds[4 * 1096];  // per wave: rows 8*132, sex 8*5
  int tid = threadIdx.x;
  int wv = tid >> 6, lane = tid & 63;
  float* rows = &lds[wv * 1096];
  float* sex = rows + 1056;

  int n = blockIdx.x * 4 + wv;
  if (n >= N) return;

  int e8 = lane >> 3;  // edge slot in batch
  int r = lane & 7;    // 16-channel chunk
  int cA = r * 16;
  int elem4 = lane & 31, jhalf = lane >> 5;
  int hL = lane >> 4;  // head for phase-B channel pair c0=2*lane

  // loop-invariant: weights+att (64 VGPR) and xr chunk (16 VGPR)
  float4 wreg[16];
  float xrA[16];
#pragma unroll
  for (int i = 0; i < 16; ++i) {
    int c = cA + i;
    wreg[i] = make_float4(We[c * 3], We[c * 3 + 1], We[c * 3 + 2], att[c]);
    xrA[i] = xr[(size_t)n * 128 + c];
  }

  int beg = rowptr[n], end = rowptr[n + 1];

  float acc0 = 0.f, acc1 = 0.f, den = 0.f;
  float es0 = 0.f, es1 = 0.f, es2 = 0.f;

  // prefetch first batch meta
  int s_pf[4];
  float4 ea_pf;
#pragma unroll
  for (int rr = 0; rr < 4; ++rr) {
    int gi = beg + rr * 2 + jhalf;
    s_pf[rr] = (gi < end) ? srcs[gi] : n;
  }
  {
    int ge = beg + e8;
    ea_pf = (ge < end) ? ea4[ge] : make_float4(0.f, 0.f, 0.f, 0.f);
  }

  for (int base = beg; base < end; base += 8) {
    // gather this batch's rows into regs
    float4 rbuf[4];
#pragma unroll
    for (int rr = 0; rr < 4; ++rr)
      rbuf[rr] = ((const float4*)xl)[(size_t)s_pf[rr] * 32 + elem4];
    float4 ea_cur = ea_pf;
    bool valid = (base + e8) < end;
    // prefetch next batch meta (overlaps with compute below)
    {
      int b = base + 8;
#pragma unroll
      for (int rr = 0; rr < 4; ++rr) {
        int gi = b + rr * 2 + jhalf;
        s_pf[rr] = (gi < end) ? srcs[gi] : n;
      }
      int ge = b + e8;
      ea_pf = (ge < end) ? ea4[ge] : make_float4(0.f, 0.f, 0.f, 0.f);
    }
    wbar();
#pragma unroll
    for (int rr = 0; rr < 4; ++rr)
      *(float4*)&rows[(rr * 2 + jhalf) * 132 + elem4 * 4] = rbuf[rr];
    wbar();
    // phase A: score for (edge e8, chunk cA) from LDS rows + reg weights
    if (valid) { es0 += ea_cur.x; es1 += ea_cur.y; es2 += ea_cur.z; }
    float v = 0.f;
    const float4* rv4 = (const float4*)&rows[e8 * 132 + cA];
#pragma unroll
    for (int i4 = 0; i4 < 4; ++i4) {
      float4 rv = rv4[i4];
#pragma unroll
      for (int q = 0; q < 4; ++q) {
        int i = i4 * 4 + q;
        float4 w = wreg[i];
        float rvq = (q == 0) ? rv.x : (q == 1) ? rv.y : (q == 2) ? rv.z : rv.w;
        float m = rvq + xrA[i] + ea_cur.x * w.x + ea_cur.y * w.y + ea_cur.z * w.z;
        m = fmaxf(m, 0.2f * m);
        v = fmaf(m, w.w, v);
      }
    }
    v += __shfl_xor(v, 1);  // combine the two 16-ch chunks of the head
    float ex = valid ? __expf(v) : 0.f;
    if ((r & 1) == 0) sex[e8 * 5 + (r >> 1)] = ex;
    wbar();
    // phase B: channel pair c0 = 2*lane (same head -> shared ex)
#pragma unroll
    for (int j = 0; j < 8; ++j) {
      float exj = sex[j * 5 + hL];
      float2 xlv = *(const float2*)&rows[j * 132 + 2 * lane];
      acc0 = fmaf(exj, xlv.x, acc0);
      acc1 = fmaf(exj, xlv.y, acc1);
      den += exj;
    }
  }

  // ---- self loop (attr = mean of incoming; each edge counted 8x above) ----
#pragma unroll
  for (int off = 1; off < 64; off <<= 1) {
    es0 += __shfl_xor(es0, off);
    es1 += __shfl_xor(es1, off);
    es2 += __shfl_xor(es2, off);
  }
  float inv = 1.0f / (8.0f * fmaxf((float)(end - beg), 1.0f));
  es0 *= inv; es1 *= inv; es2 *= inv;

  int c0 = 2 * lane;
  float2 xls = *(const float2*)&xl[(size_t)n * 128 + c0];
  float2 xrv = *(const float2*)&xr[(size_t)n * 128 + c0];
  float4 w0 = make_float4(We[c0 * 3], We[c0 * 3 + 1], We[c0 * 3 + 2], att[c0]);
  float4 w1 = make_float4(We[c0 * 3 + 3], We[c0 * 3 + 4], We[c0 * 3 + 5], att[c0 + 1]);
  float m0 = xls.x + xrv.x + es0 * w0.x + es1 * w0.y + es2 * w0.z;
  m0 = fmaxf(m0, 0.2f * m0);
  float m1 = xls.y + xrv.y + es0 * w1.x + es1 * w1.y + es2 * w1.z;
  m1 = fmaxf(m1, 0.2f * m1);
  float t = m0 * w0.w + m1 * w1.w;
#pragma unroll
  for (int off = 1; off < 16; off <<= 1) t += __shfl_xor(t, off);  // 16-lane head group
  float ex = __expf(t);
  den += ex;
  acc0 = fmaf(ex, xls.x, acc0);
  acc1 = fmaf(ex, xls.y, acc1);

  float o0 = acc0 / den + bias[c0];
  float o1 = acc1 / den + bias[c0 + 1];
  o0 = o0 > 0.f ? o0 : __expf(o0) - 1.0f;  // ELU
  o1 = o1 > 0.f ? o1 : __expf(o1) - 1.0f;
  *(float2*)&out[(size_t)n * 128 + c0] = make_float2(o0, o1);
}

// ---------------- fused GATv2 layer 2 (H=1, C=64, mean) ---------------------
__global__ __launch_bounds__(256, 4) void gat2_fused_k(
    const int* __restrict__ rowptr, const int* __restrict__ srcs,
    const float4* __restrict__ ea4, const float* __restrict__ xl,
    const float* __restrict__ xr, const float* __restrict__ We,
    const float* __restrict__ att, const float* __restrict__ bias,
    float* __restrict__ out, int N) {
  __shared__ __align__(16) float lds[4 * 552];  // per wave: rows 8*68, sex 8
  int tid = threadIdx.x;
  int wv = tid >> 6, lane = tid & 63;
  float* rows = &lds[wv * 552];
  float* sex = rows + 544;

  int n = blockIdx.x * 4 + wv;
  if (n >= N) return;

  int e8 = lane >> 3;
  int oct = lane & 7;
  int cB = oct * 8;
  int elem4 = lane & 15, jq = lane >> 4;

  // loop-invariant: weights+att (32 VGPR) and xr chunk (8 VGPR)
  float4 wreg[8];
  float xrA[8];
#pragma unroll
  for (int i = 0; i < 8; ++i) {
    int c = cB + i;
    wreg[i] = make_float4(We[c * 3], We[c * 3 + 1], We[c * 3 + 2], att[c]);
    xrA[i] = xr[(size_t)n * 64 + c];
  }

  int beg = rowptr[n], end = rowptr[n + 1];

  float acc = 0.f, den = 0.f;
  float es0 = 0.f, es1 = 0.f, es2 = 0.f;

  int s_pf[2];
  float4 ea_pf;
#pragma unroll
  for (int rr = 0; rr < 2; ++rr) {
    int gi = beg + rr * 4 + jq;
    s_pf[rr] = (gi < end) ? srcs[gi] : n;
  }
  {
    int ge = beg + e8;
    ea_pf = (ge < end) ? ea4[ge] : make_float4(0.f, 0.f, 0.f, 0.f);
  }

  for (int base = beg; base < end; base += 8) {
    float4 rbuf[2];
#pragma unroll
    for (int rr = 0; rr < 2; ++rr)
      rbuf[rr] = ((const float4*)xl)[(size_t)s_pf[rr] * 16 + elem4];
    float4 ea_cur = ea_pf;
    bool valid = (base + e8) < end;
    {
      int b = base + 8;
#pragma unroll
      for (int rr = 0; rr < 2; ++rr) {
        int gi = b + rr * 4 + jq;
        s_pf[rr] = (gi < end) ? srcs[gi] : n;
      }
      int ge = b + e8;
      ea_pf = (ge < end) ? ea4[ge] : make_float4(0.f, 0.f, 0.f, 0.f);
    }
    wbar();
#pragma unroll
    for (int rr = 0; rr < 2; ++rr)
      *(float4*)&rows[(rr * 4 + jq) * 68 + elem4 * 4] = rbuf[rr];
    wbar();
    if (valid) { es0 += ea_cur.x; es1 += ea_cur.y; es2 += ea_cur.z; }
    float v = 0.f;
    const float4* rv4 = (const float4*)&rows[e8 * 68 + cB];
#pragma unroll
    for (int i4 = 0; i4 < 2; ++i4) {
      float4 rv = rv4[i4];
#pragma unroll
      for (int q = 0; q < 4; ++q) {
        int i = i4 * 4 + q;
        float4 w = wreg[i];
        float rvq = (q == 0) ? rv.x : (q == 1) ? rv.y : (q == 2) ? rv.z : rv.w;
        float m = rvq + xrA[i] + ea_cur.x * w.x + ea_cur.y * w.y + ea_cur.z * w.z;
        m = fmaxf(m, 0.2f * m);
        v = fmaf(m, w.w, v);
      }
    }
    v += __shfl_xor(v, 1);
    v += __shfl_xor(v, 2);
    v += __shfl_xor(v, 4);
    float ex = valid ? __expf(v) : 0.f;
    if (oct == 0) sex[e8] = ex;
    wbar();
#pragma unroll
    for (int j = 0; j < 8; ++j) {
      float exj = sex[j];
      acc = fmaf(exj, rows[j * 68 + lane], acc);
      den += exj;
    }
  }

#pragma unroll
  for (int off = 1; off < 64; off <<= 1) {
    es0 += __shfl_xor(es0, off);
    es1 += __shfl_xor(es1, off);
    es2 += __shfl_xor(es2, off);
  }
  float inv = 1.0f / (8.0f * fmaxf((float)(end - beg), 1.0f));
  es0 *= inv; es1 *= inv; es2 *= inv;

  float xlsv = xl[(size_t)n * 64 + lane];
  float xrv = xr[(size_t)n * 64 + lane];
  float4 w = make_float4(We[lane * 3], We[lane * 3 + 1], We[lane * 3 + 2], att[lane]);
  float m = xlsv + xrv + es0 * w.x + es1 * w.y + es2 * w.z;
  m = fmaxf(m, 0.2f * m);
  float t = m * w.w;
#pragma unroll
  for (int off = 1; off < 64; off <<= 1) t += __shfl_xor(t, off);
  float ex = __expf(t);
  den += ex;
  acc = fmaf(ex, xlsv, acc);

  float o = acc / den + bias[lane];
  o = o > 0.f ? o : __expf(o) - 1.0f;  // ELU
  out[(size_t)n * 64 + lane] = o;
}

// ---------------- mean pool over batch --------------------------------------
__global__ void pool_k(const float* __restrict__ h2, const int* __restrict__ batch,
                       float* __restrict__ pooled, float* __restrict__ cntg, int N) {
  long t = (long)blockIdx.x * blockDim.x + threadIdx.x;
  int n = (int)(t >> 6);
  int c = (int)(t & 63);
  if (n >= N) return;
  int g = batch[n];
  atomicAdd(&pooled[(size_t)g * 64 + c], h2[(size_t)n * 64 + c]);
  if (c == 0) atomicAdd(&cntg[g], 1.0f);
}

// ---------------- final MLP head --------------------------------------------
__global__ void final_mlp_k(const float* __restrict__ pooled, const float* __restrict__ cntg,
                            const float* __restrict__ u, const float* __restrict__ W1,
                            const float* __restrict__ b1, const float* __restrict__ Wh,
                            const float* __restrict__ bh, float* __restrict__ out) {
  __shared__ float feat[65];
  __shared__ float z[32];
  int g = blockIdx.x;
  int t = threadIdx.x;  // 64 threads
  float inv = 1.0f / fmaxf(cntg[g], 1.0f);
  feat[t] = pooled[(size_t)g * 64 + t] * inv;
  if (t == 0) feat[64] = u[g];
  __syncthreads();
  if (t < 32) {
    float a = b1[t];
    for (int k = 0; k < 65; ++k) a += feat[k] * W1[t * 65 + k];
    z[t] = fmaxf(a, 0.0f);
  }
  __syncthreads();
  if (t < 10) {
    float a = bh[t];
    for (int k = 0; k < 32; ++k) a += z[k] * Wh[t * 32 + k];
    out[g * 10 + t] = a;
  }
}

// ---------------------------------------------------------------------------
extern "C" void kernel_launch(void* const* d_in, const int* in_sizes, int n_in,
                              void* d_out, int out_size, void* d_ws, size_t ws_size,
                              hipStream_t stream) {
  const float* x      = (const float*)d_in[0];
  const int*   eidx   = (const int*)d_in[1];
  const float* eattr  = (const float*)d_in[2];
  const int*   batch  = (const int*)d_in[3];
  const float* u      = (const float*)d_in[4];
  const float* Wl1    = (const float*)d_in[5];
  const float* bl1    = (const float*)d_in[6];
  const float* Wr1    = (const float*)d_in[7];
  const float* br1    = (const float*)d_in[8];
  const float* We1    = (const float*)d_in[9];
  const float* att1   = (const float*)d_in[10];
  const float* b1     = (const float*)d_in[11];
  const float* Wl2    = (const float*)d_in[12];
  const float* bl2    = (const float*)d_in[13];
  const float* Wr2    = (const float*)d_in[14];
  const float* br2    = (const float*)d_in[15];
  const float* We2    = (const float*)d_in[16];
  const float* att2   = (const float*)d_in[17];
  const float* b2     = (const float*)d_in[18];
  const float* W_lin1 = (const float*)d_in[19];
  const float* b_lin1 = (const float*)d_in[20];
  const float* W_head = (const float*)d_in[21];
  const float* b_head = (const float*)d_in[22];

  const int N = in_sizes[0] / 128;
  const int E = in_sizes[1] / 2;
  const int G = in_sizes[4];
  const int* srcp = eidx;
  const int* dstp = eidx + E;

  // ---- workspace layout ----
  float* buf1 = (float*)d_ws;                       // xl1 (N*128) -> xl2 (N*64)
  float* buf2 = buf1 + (size_t)N * 128;             // xr1 (N*128) -> xr2 (N*64)
  float* buf3 = buf2 + (size_t)N * 128;             // h1  (N*128) -> h2  (N*64)
  float4* ea4 = (float4*)(buf3 + (size_t)N * 128);  // E sorted edge attrs
  int* srcs_s = (int*)(ea4 + E);                    // E sorted src ids
  int* deg    = srcs_s + E;                         // N
  int* rowptr = deg + N;                            // N+1
  int* cursor = rowptr + N + 1;                     // N
  int* bsum   = cursor + N;                         // 256
  float* pooled = (float*)(bsum + 256);             // G*64
  float* pcnt   = pooled + (size_t)G * 64;          // G

  const int nb = (N + 255) / 256;

  // ---- CSR build (sort edges by dst) ----
  hipMemsetAsync(deg, 0, sizeof(int) * (size_t)N, stream);
  hist_k<<<(E + 255) / 256, 256, 0, stream>>>(dstp, deg, E);
  blocksum_k<<<nb, 256, 0, stream>>>(deg, bsum, N);
  scan_bsum_k<<<1, 256, 0, stream>>>(bsum, nb);
  writeptr_k<<<nb, 256, 0, stream>>>(deg, bsum, rowptr, cursor, N, E);
  fill_k<<<(E + 255) / 256, 256, 0, stream>>>(srcp, dstp, eattr, cursor, srcs_s, ea4, E);

  // ---- layer 1 ----
  node_linear2_k<128, 32><<<(N + 31) / 32, 256, 0, stream>>>(x, Wl1, bl1, Wr1, br1,
                                                             buf1, buf2, N);
  gat1_fused_k<<<(N + 3) / 4, 256, 0, stream>>>(rowptr, srcs_s, ea4, buf1, buf2,
                                                We1, att1, b1, buf3, N);

  // ---- layer 2 ----
  node_linear2_k<64, 64><<<(N + 63) / 64, 256, 0, stream>>>(buf3, Wl2, bl2, Wr2, br2,
                                                            buf1, buf2, N);
  gat2_fused_k<<<(N + 3) / 4, 256, 0, stream>>>(rowptr, srcs_s, ea4, buf1, buf2,
                                                We2, att2, b2, buf3, N);

  // ---- pool + head ----
  hipMemsetAsync(pooled, 0, sizeof(float) * ((size_t)G * 64 + G), stream);
  pool_k<<<((long)N * 64 + 255) / 256, 256, 0, stream>>>(buf3, batch, pooled, pcnt, N);
  final_mlp_k<<<G, 64, 0, stream>>>(pooled, pcnt, u, W_lin1, b_lin1, W_head, b_head,
                                    (float*)d_out);
}

// Round 5
// 726.304 us; speedup vs baseline: 1.0254x; 1.0254x over previous
//
#include <hip/hip_runtime.h>
#include <math.h>

// ---------------------------------------------------------------------------
// TacticalGAT round 5: block-per-node fused GATv2 (4 waves/node, 16 edges per
// block-iteration).  16-lane-per-edge scoring keeps per-lane weight footprint
// at 8 float4 (32 VGPR, no spill; r4's wreg[16] spilled to scratch -> 147MB
// writes).  Rows staged once in wave-private LDS, reused score+aggregate;
// cross-wave combine via LDS.  launch_bounds(256,2) -> 256-VGPR cap.
// ---------------------------------------------------------------------------

__device__ __forceinline__ void wbar() { __builtin_amdgcn_wave_barrier(); }

// ---------------- CSR build -------------------------------------------------
__global__ void hist_k(const int* __restrict__ dst, int* __restrict__ deg, int E) {
  int e = blockIdx.x * 256 + threadIdx.x;
  if (e < E) atomicAdd(&deg[dst[e]], 1);
}

__global__ void blocksum_k(const int* __restrict__ deg, int* __restrict__ bsum, int N) {
  __shared__ int s[256];
  int i = blockIdx.x * 256 + threadIdx.x;
  s[threadIdx.x] = (i < N) ? deg[i] : 0;
  __syncthreads();
  for (int off = 128; off; off >>= 1) {
    if (threadIdx.x < off) s[threadIdx.x] += s[threadIdx.x + off];
    __syncthreads();
  }
  if (threadIdx.x == 0) bsum[blockIdx.x] = s[0];
}

__global__ void scan_bsum_k(int* __restrict__ bsum, int nb) {
  __shared__ int s[256];
  int t = threadIdx.x;
  s[t] = (t < nb) ? bsum[t] : 0;
  __syncthreads();
  for (int off = 1; off < 256; off <<= 1) {
    int v = (t >= off) ? s[t - off] : 0;
    __syncthreads();
    if (t >= off) s[t] += v;
    __syncthreads();
  }
  int excl = (t == 0) ? 0 : s[t - 1];
  if (t < nb) bsum[t] = excl;
}

__global__ void writeptr_k(const int* __restrict__ deg, const int* __restrict__ bsum,
                           int* __restrict__ rowptr, int* __restrict__ cursor, int N, int E) {
  __shared__ int s[256];
  int t = threadIdx.x;
  int i = blockIdx.x * 256 + t;
  s[t] = (i < N) ? deg[i] : 0;
  __syncthreads();
  for (int off = 1; off < 256; off <<= 1) {
    int v = (t >= off) ? s[t - off] : 0;
    __syncthreads();
    if (t >= off) s[t] += v;
    __syncthreads();
  }
  int excl = bsum[blockIdx.x] + ((t == 0) ? 0 : s[t - 1]);
  if (i < N) {
    rowptr[i] = excl;
    cursor[i] = excl;
  }
  if (i == N - 1) rowptr[N] = E;
}

__global__ void fill_k(const int* __restrict__ src, const int* __restrict__ dst,
                       const float* __restrict__ eattr, int* __restrict__ cursor,
                       int* __restrict__ srcs_s, float4* __restrict__ ea4, int E) {
  int e = blockIdx.x * 256 + threadIdx.x;
  if (e >= E) return;
  int d = dst[e];
  int pos = atomicAdd(&cursor[d], 1);
  srcs_s[pos] = src[e];
  ea4[pos] = make_float4(eattr[e * 3 + 0], eattr[e * 3 + 1], eattr[e * 3 + 2], 0.0f);
}

// ---------------- fused dual node linear (Wl & Wr share X reads) ------------
template <int J, int RB>
__global__ __launch_bounds__(256) void node_linear2_k(
    const float* __restrict__ X,
    const float* __restrict__ W1, const float* __restrict__ b1v,
    const float* __restrict__ W2, const float* __restrict__ b2v,
    float* __restrict__ out1, float* __restrict__ out2, int nrows) {
  constexpr int K = 128, KB = 32;
  constexpr int JG = J / 4;
  static_assert((JG * (RB / 4)) == 256, "tile mismatch");
  __shared__ __align__(16) float sW1[KB][J];
  __shared__ __align__(16) float sW2[KB][J];
  __shared__ float sX[RB][K + 1];

  int n0 = blockIdx.x * RB;
  for (int idx = threadIdx.x; idx < RB * K; idx += 256) {
    int rr = idx >> 7, k = idx & 127;
    int n = n0 + rr;
    sX[rr][k] = (n < nrows) ? X[(size_t)n * K + k] : 0.0f;
  }
  int jg = threadIdx.x % JG;
  int rg = threadIdx.x / JG;

  float acc1[4][4] = {}, acc2[4][4] = {};
  for (int kb = 0; kb < 4; ++kb) {
    __syncthreads();
    for (int idx = threadIdx.x; idx < KB * J; idx += 256) {
      int j = idx % J, k = idx / J;
      sW1[k][j] = W1[j * K + kb * KB + k];
      sW2[k][j] = W2[j * K + kb * KB + k];
    }
    __syncthreads();
#pragma unroll
    for (int k = 0; k < KB; ++k) {
      float4 wa = *(const float4*)&sW1[k][jg * 4];
      float4 wb = *(const float4*)&sW2[k][jg * 4];
#pragma unroll
      for (int i = 0; i < 4; ++i) {
        float xv = sX[rg * 4 + i][kb * KB + k];
        acc1[i][0] += xv * wa.x; acc1[i][1] += xv * wa.y;
        acc1[i][2] += xv * wa.z; acc1[i][3] += xv * wa.w;
        acc2[i][0] += xv * wb.x; acc2[i][1] += xv * wb.y;
        acc2[i][2] += xv * wb.z; acc2[i][3] += xv * wb.w;
      }
    }
  }
  float4 bv1 = *(const float4*)&b1v[jg * 4];
  float4 bv2 = *(const float4*)&b2v[jg * 4];
#pragma unroll
  for (int i = 0; i < 4; ++i) {
    int n = n0 + rg * 4 + i;
    if (n < nrows) {
      float4 o1 = make_float4(acc1[i][0] + bv1.x, acc1[i][1] + bv1.y,
                              acc1[i][2] + bv1.z, acc1[i][3] + bv1.w);
      float4 o2 = make_float4(acc2[i][0] + bv2.x, acc2[i][1] + bv2.y,
                              acc2[i][2] + bv2.z, acc2[i][3] + bv2.w);
      *(float4*)&out1[(size_t)n * J + jg * 4] = o1;
      *(float4*)&out2[(size_t)n * J + jg * 4] = o2;
    }
  }
}

// ---------------- fused GATv2 layer 1 (H=4, C=32, concat) -------------------
// one block (4 waves) per node; 16 edges per block-iteration (4 per wave);
// 16 lanes score one edge (8 ch each, wreg[8]=32 VGPR).
__global__ __launch_bounds__(256, 2) void gat1_fused_k(
    const int* __restrict__ rowptr, const int* __restrict__ srcs,
    const float4* __restrict__ ea4, const float* __restrict__ xl,
    const float* __restrict__ xr, const float* __restrict__ We,
    const float* __restrict__ att, const float* __restrict__ bias,
    float* __restrict__ out, int N) {
  __shared__ __align__(16) float rows[16 * 132];
  __shared__ float sex[16 * 5];
  __shared__ float comb[4 * 64 * 3];
  __shared__ float comb_es[4 * 4];

  int tid = threadIdx.x;
  int wv = tid >> 6, lane = tid & 63;
  int n = blockIdx.x;
  int e4 = lane >> 4;       // wave-local edge slot (0..3)
  int r = lane & 15;        // 8-channel chunk within the edge
  int cA = r * 8;
  int h = r >> 2;           // head of this chunk
  int hL = lane >> 4;       // phase-B head for channel pair c0 = 2*lane
  int eslot = wv * 4 + e4;  // block edge slot (0..15)

  float4 wreg[8];
  float xrA[8];
#pragma unroll
  for (int i = 0; i < 8; ++i) {
    int c = cA + i;
    wreg[i] = make_float4(We[c * 3], We[c * 3 + 1], We[c * 3 + 2], att[c]);
    xrA[i] = xr[(size_t)n * 128 + c];
  }
  int beg = rowptr[n], end = rowptr[n + 1];

  float acc0 = 0.f, acc1 = 0.f, den = 0.f;
  float es0 = 0.f, es1 = 0.f, es2 = 0.f;

  for (int base = beg; base < end; base += 16) {
    int gi = base + eslot;
    bool valid = gi < end;
    int s = valid ? srcs[gi] : 0;
    float4 ea = valid ? ea4[gi] : make_float4(0.f, 0.f, 0.f, 0.f);
    float4 r0 = make_float4(0.f, 0.f, 0.f, 0.f), r1 = r0;
    if (valid) {
      const float4* rp = (const float4*)&xl[(size_t)s * 128 + cA];
      r0 = rp[0];
      r1 = rp[1];
    }
    if (r == 0 && valid) { es0 += ea.x; es1 += ea.y; es2 += ea.z; }
    // stage row chunk (zeros when invalid: avoids NaN garbage in phase B)
    *(float4*)&rows[eslot * 132 + cA] = r0;
    *(float4*)&rows[eslot * 132 + cA + 4] = r1;
    // score from registers (8 ch)
    float v = 0.f;
#pragma unroll
    for (int q = 0; q < 8; ++q) {
      float xv = (q == 0) ? r0.x : (q == 1) ? r0.y : (q == 2) ? r0.z : (q == 3) ? r0.w
               : (q == 4) ? r1.x : (q == 5) ? r1.y : (q == 6) ? r1.z : r1.w;
      float4 w = wreg[q];
      float m = xv + xrA[q] + ea.x * w.x + ea.y * w.y + ea.z * w.z;
      m = fmaxf(m, 0.2f * m);
      v = fmaf(m, w.w, v);
    }
    v += __shfl_xor(v, 1);
    v += __shfl_xor(v, 2);  // head = 4-lane group
    float ex = valid ? __expf(v) : 0.f;
    if ((r & 3) == 0) sex[eslot * 5 + h] = ex;
    wbar();
    // aggregate this wave's 4 edges (channel pair c0 = 2*lane)
#pragma unroll
    for (int j = 0; j < 4; ++j) {
      int sl = wv * 4 + j;
      float exj = sex[sl * 5 + hL];
      float2 xlv = *(const float2*)&rows[sl * 132 + 2 * lane];
      acc0 = fmaf(exj, xlv.x, acc0);
      acc1 = fmaf(exj, xlv.y, acc1);
      den += exj;
    }
    wbar();
  }

  // cross-wave combine
  es0 += __shfl_xor(es0, 16); es0 += __shfl_xor(es0, 32);
  es1 += __shfl_xor(es1, 16); es1 += __shfl_xor(es1, 32);
  es2 += __shfl_xor(es2, 16); es2 += __shfl_xor(es2, 32);
  if (lane == 0) {
    comb_es[wv * 4 + 0] = es0;
    comb_es[wv * 4 + 1] = es1;
    comb_es[wv * 4 + 2] = es2;
  }
  float* cb = &comb[(wv * 64 + lane) * 3];
  cb[0] = acc0; cb[1] = acc1; cb[2] = den;
  __syncthreads();
  if (wv != 0) return;

  acc0 = 0.f; acc1 = 0.f; den = 0.f;
#pragma unroll
  for (int w = 0; w < 4; ++w) {
    const float* cw = &comb[(w * 64 + lane) * 3];
    acc0 += cw[0]; acc1 += cw[1]; den += cw[2];
  }
  float et0 = comb_es[0] + comb_es[4] + comb_es[8] + comb_es[12];
  float et1 = comb_es[1] + comb_es[5] + comb_es[9] + comb_es[13];
  float et2 = comb_es[2] + comb_es[6] + comb_es[10] + comb_es[14];
  float inv = 1.0f / fmaxf((float)(end - beg), 1.0f);
  et0 *= inv; et1 *= inv; et2 *= inv;

  // self loop
  int c0 = 2 * lane;
  float2 xls = *(const float2*)&xl[(size_t)n * 128 + c0];
  float2 xrv = *(const float2*)&xr[(size_t)n * 128 + c0];
  float m0 = xls.x + xrv.x + et0 * We[c0 * 3] + et1 * We[c0 * 3 + 1] + et2 * We[c0 * 3 + 2];
  m0 = fmaxf(m0, 0.2f * m0);
  float m1 = xls.y + xrv.y + et0 * We[c0 * 3 + 3] + et1 * We[c0 * 3 + 4] + et2 * We[c0 * 3 + 5];
  m1 = fmaxf(m1, 0.2f * m1);
  float t = m0 * att[c0] + m1 * att[c0 + 1];
#pragma unroll
  for (int off = 1; off < 16; off <<= 1) t += __shfl_xor(t, off);  // 16-lane head group
  float ex = __expf(t);
  den += ex;
  acc0 = fmaf(ex, xls.x, acc0);
  acc1 = fmaf(ex, xls.y, acc1);

  float o0 = acc0 / den + bias[c0];
  float o1 = acc1 / den + bias[c0 + 1];
  o0 = o0 > 0.f ? o0 : __expf(o0) - 1.0f;  // ELU
  o1 = o1 > 0.f ? o1 : __expf(o1) - 1.0f;
  *(float2*)&out[(size_t)n * 128 + c0] = make_float2(o0, o1);
}

// ---------------- fused GATv2 layer 2 (H=1, C=64, mean) ---------------------
__global__ __launch_bounds__(256, 2) void gat2_fused_k(
    const int* __restrict__ rowptr, const int* __restrict__ srcs,
    const float4* __restrict__ ea4, const float* __restrict__ xl,
    const float* __restrict__ xr, const float* __restrict__ We,
    const float* __restrict__ att, const float* __restrict__ bias,
    float* __restrict__ out, int N) {
  __shared__ __align__(16) float rows[16 * 68];
  __shared__ float sex[16];
  __shared__ float comb[4 * 64 * 2];
  __shared__ float comb_es[4 * 4];

  int tid = threadIdx.x;
  int wv = tid >> 6, lane = tid & 63;
  int n = blockIdx.x;
  int e4 = lane >> 4;
  int r = lane & 15;  // 4-channel chunk
  int cA = r * 4;
  int eslot = wv * 4 + e4;

  float4 wreg[4];
  float xrA[4];
#pragma unroll
  for (int i = 0; i < 4; ++i) {
    int c = cA + i;
    wreg[i] = make_float4(We[c * 3], We[c * 3 + 1], We[c * 3 + 2], att[c]);
    xrA[i] = xr[(size_t)n * 64 + c];
  }
  int beg = rowptr[n], end = rowptr[n + 1];

  float acc = 0.f, den = 0.f;
  float es0 = 0.f, es1 = 0.f, es2 = 0.f;

  for (int base = beg; base < end; base += 16) {
    int gi = base + eslot;
    bool valid = gi < end;
    int s = valid ? srcs[gi] : 0;
    float4 ea = valid ? ea4[gi] : make_float4(0.f, 0.f, 0.f, 0.f);
    float4 r0 = make_float4(0.f, 0.f, 0.f, 0.f);
    if (valid) r0 = *(const float4*)&xl[(size_t)s * 64 + cA];
    if (r == 0 && valid) { es0 += ea.x; es1 += ea.y; es2 += ea.z; }
    *(float4*)&rows[eslot * 68 + cA] = r0;
    float v = 0.f;
#pragma unroll
    for (int q = 0; q < 4; ++q) {
      float xv = (q == 0) ? r0.x : (q == 1) ? r0.y : (q == 2) ? r0.z : r0.w;
      float4 w = wreg[q];
      float m = xv + xrA[q] + ea.x * w.x + ea.y * w.y + ea.z * w.z;
      m = fmaxf(m, 0.2f * m);
      v = fmaf(m, w.w, v);
    }
    v += __shfl_xor(v, 1);
    v += __shfl_xor(v, 2);
    v += __shfl_xor(v, 4);
    v += __shfl_xor(v, 8);  // 16-lane edge group
    float ex = valid ? __expf(v) : 0.f;
    if (r == 0) sex[eslot] = ex;
    wbar();
#pragma unroll
    for (int j = 0; j < 4; ++j) {
      int sl = wv * 4 + j;
      float exj = sex[sl];
      acc = fmaf(exj, rows[sl * 68 + lane], acc);
      den += exj;
    }
    wbar();
  }

  es0 += __shfl_xor(es0, 16); es0 += __shfl_xor(es0, 32);
  es1 += __shfl_xor(es1, 16); es1 += __shfl_xor(es1, 32);
  es2 += __shfl_xor(es2, 16); es2 += __shfl_xor(es2, 32);
  if (lane == 0) {
    comb_es[wv * 4 + 0] = es0;
    comb_es[wv * 4 + 1] = es1;
    comb_es[wv * 4 + 2] = es2;
  }
  float* cb = &comb[(wv * 64 + lane) * 2];
  cb[0] = acc; cb[1] = den;
  __syncthreads();
  if (wv != 0) return;

  acc = 0.f; den = 0.f;
#pragma unroll
  for (int w = 0; w < 4; ++w) {
    const float* cw = &comb[(w * 64 + lane) * 2];
    acc += cw[0]; den += cw[1];
  }
  float et0 = comb_es[0] + comb_es[4] + comb_es[8] + comb_es[12];
  float et1 = comb_es[1] + comb_es[5] + comb_es[9] + comb_es[13];
  float et2 = comb_es[2] + comb_es[6] + comb_es[10] + comb_es[14];
  float inv = 1.0f / fmaxf((float)(end - beg), 1.0f);
  et0 *= inv; et1 *= inv; et2 *= inv;

  float xls = xl[(size_t)n * 64 + lane];
  float xrv = xr[(size_t)n * 64 + lane];
  float m = xls + xrv + et0 * We[lane * 3] + et1 * We[lane * 3 + 1] + et2 * We[lane * 3 + 2];
  m = fmaxf(m, 0.2f * m);
  float t = m * att[lane];
#pragma unroll
  for (int off = 1; off < 64; off <<= 1) t += __shfl_xor(t, off);
  float ex = __expf(t);
  den += ex;
  acc = fmaf(ex, xls, acc);

  float o = acc / den + bias[lane];
  o = o > 0.f ? o : __expf(o) - 1.0f;  // ELU
  out[(size_t)n * 64 + lane] = o;
}

// ---------------- mean pool over batch --------------------------------------
__global__ void pool_k(const float* __restrict__ h2, const int* __restrict__ batch,
                       float* __restrict__ pooled, float* __restrict__ cntg, int N) {
  long t = (long)blockIdx.x * blockDim.x + threadIdx.x;
  int n = (int)(t >> 6);
  int c = (int)(t & 63);
  if (n >= N) return;
  int g = batch[n];
  atomicAdd(&pooled[(size_t)g * 64 + c], h2[(size_t)n * 64 + c]);
  if (c == 0) atomicAdd(&cntg[g], 1.0f);
}

// ---------------- final MLP head --------------------------------------------
__global__ void final_mlp_k(const float* __restrict__ pooled, const float* __restrict__ cntg,
                            const float* __restrict__ u, const float* __restrict__ W1,
                            const float* __restrict__ b1, const float* __restrict__ Wh,
                            const float* __restrict__ bh, float* __restrict__ out) {
  __shared__ float feat[65];
  __shared__ float z[32];
  int g = blockIdx.x;
  int t = threadIdx.x;  // 64 threads
  float inv = 1.0f / fmaxf(cntg[g], 1.0f);
  feat[t] = pooled[(size_t)g * 64 + t] * inv;
  if (t == 0) feat[64] = u[g];
  __syncthreads();
  if (t < 32) {
    float a = b1[t];
    for (int k = 0; k < 65; ++k) a += feat[k] * W1[t * 65 + k];
    z[t] = fmaxf(a, 0.0f);
  }
  __syncthreads();
  if (t < 10) {
    float a = bh[t];
    for (int k = 0; k < 32; ++k) a += z[k] * Wh[t * 32 + k];
    out[g * 10 + t] = a;
  }
}

// ---------------------------------------------------------------------------
extern "C" void kernel_launch(void* const* d_in, const int* in_sizes, int n_in,
                              void* d_out, int out_size, void* d_ws, size_t ws_size,
                              hipStream_t stream) {
  const float* x      = (const float*)d_in[0];
  const int*   eidx   = (const int*)d_in[1];
  const float* eattr  = (const float*)d_in[2];
  const int*   batch  = (const int*)d_in[3];
  const float* u      = (const float*)d_in[4];
  const float* Wl1    = (const float*)d_in[5];
  const float* bl1    = (const float*)d_in[6];
  const float* Wr1    = (const float*)d_in[7];
  const float* br1    = (const float*)d_in[8];
  const float* We1    = (const float*)d_in[9];
  const float* att1   = (const float*)d_in[10];
  const float* b1     = (const float*)d_in[11];
  const float* Wl2    = (const float*)d_in[12];
  const float* bl2    = (const float*)d_in[13];
  const float* Wr2    = (const float*)d_in[14];
  const float* br2    = (const float*)d_in[15];
  const float* We2    = (const float*)d_in[16];
  const float* att2   = (const float*)d_in[17];
  const float* b2     = (const float*)d_in[18];
  const float* W_lin1 = (const float*)d_in[19];
  const float* b_lin1 = (const float*)d_in[20];
  const float* W_head = (const float*)d_in[21];
  const float* b_head = (const float*)d_in[22];

  const int N = in_sizes[0] / 128;
  const int E = in_sizes[1] / 2;
  const int G = in_sizes[4];
  const int* srcp = eidx;
  const int* dstp = eidx + E;

  // ---- workspace layout ----
  float* buf1 = (float*)d_ws;                       // xl1 (N*128) -> xl2 (N*64)
  float* buf2 = buf1 + (size_t)N * 128;             // xr1 (N*128) -> xr2 (N*64)
  float* buf3 = buf2 + (size_t)N * 128;             // h1  (N*128) -> h2  (N*64)
  float4* ea4 = (float4*)(buf3 + (size_t)N * 128);  // E sorted edge attrs
  int* srcs_s = (int*)(ea4 + E);                    // E sorted src ids
  int* deg    = srcs_s + E;                         // N
  int* rowptr = deg + N;                            // N+1
  int* cursor = rowptr + N + 1;                     // N
  int* bsum   = cursor + N;                         // 256
  float* pooled = (float*)(bsum + 256);             // G*64
  float* pcnt   = pooled + (size_t)G * 64;          // G

  const int nb = (N + 255) / 256;

  // ---- CSR build (sort edges by dst) ----
  hipMemsetAsync(deg, 0, sizeof(int) * (size_t)N, stream);
  hist_k<<<(E + 255) / 256, 256, 0, stream>>>(dstp, deg, E);
  blocksum_k<<<nb, 256, 0, stream>>>(deg, bsum, N);
  scan_bsum_k<<<1, 256, 0, stream>>>(bsum, nb);
  writeptr_k<<<nb, 256, 0, stream>>>(deg, bsum, rowptr, cursor, N, E);
  fill_k<<<(E + 255) / 256, 256, 0, stream>>>(srcp, dstp, eattr, cursor, srcs_s, ea4, E);

  // ---- layer 1 ----
  node_linear2_k<128, 32><<<(N + 31) / 32, 256, 0, stream>>>(x, Wl1, bl1, Wr1, br1,
                                                             buf1, buf2, N);
  gat1_fused_k<<<N, 256, 0, stream>>>(rowptr, srcs_s, ea4, buf1, buf2,
                                      We1, att1, b1, buf3, N);

  // ---- layer 2 ----
  node_linear2_k<64, 64><<<(N + 63) / 64, 256, 0, stream>>>(buf3, Wl2, bl2, Wr2, br2,
                                                            buf1, buf2, N);
  gat2_fused_k<<<N, 256, 0, stream>>>(rowptr, srcs_s, ea4, buf1, buf2,
                                      We2, att2, b2, buf3, N);

  // ---- pool + head ----
  hipMemsetAsync(pooled, 0, sizeof(float) * ((size_t)G * 64 + G), stream);
  pool_k<<<((long)N * 64 + 255) / 256, 256, 0, stream>>>(buf3, batch, pooled, pcnt, N);
  final_mlp_k<<<G, 64, 0, stream>>>(pooled, pcnt, u, W_lin1, b_lin1, W_head, b_head,
                                    (float*)d_out);
}

// Round 6
// 611.817 us; speedup vs baseline: 1.2172x; 1.1871x over previous
//
#include <hip/hip_runtime.h>
#include <math.h>

// ---------------------------------------------------------------------------
// TacticalGAT round 6: GEMM rebuilt with transposed LDS operands (sXT[k][r],
// sWT[k][j]) so the inner loop is 3x ds_read_b128 + 32 FMA per k (VALU-bound),
// 52KB LDS -> 3 blocks/CU.  r5's version was scalar-LDS + 2 blocks/CU at
// 160us vs 21us compute floor.  GAT block-per-node kernels unchanged.
// ---------------------------------------------------------------------------

__device__ __forceinline__ void wbar() { __builtin_amdgcn_wave_barrier(); }

// ---------------- CSR build -------------------------------------------------
__global__ void hist_k(const int* __restrict__ dst, int* __restrict__ deg, int E) {
  int e = blockIdx.x * 256 + threadIdx.x;
  if (e < E) atomicAdd(&deg[dst[e]], 1);
}

__global__ void blocksum_k(const int* __restrict__ deg, int* __restrict__ bsum, int N) {
  __shared__ int s[256];
  int i = blockIdx.x * 256 + threadIdx.x;
  s[threadIdx.x] = (i < N) ? deg[i] : 0;
  __syncthreads();
  for (int off = 128; off; off >>= 1) {
    if (threadIdx.x < off) s[threadIdx.x] += s[threadIdx.x + off];
    __syncthreads();
  }
  if (threadIdx.x == 0) bsum[blockIdx.x] = s[0];
}

__global__ void scan_bsum_k(int* __restrict__ bsum, int nb) {
  __shared__ int s[256];
  int t = threadIdx.x;
  s[t] = (t < nb) ? bsum[t] : 0;
  __syncthreads();
  for (int off = 1; off < 256; off <<= 1) {
    int v = (t >= off) ? s[t - off] : 0;
    __syncthreads();
    if (t >= off) s[t] += v;
    __syncthreads();
  }
  int excl = (t == 0) ? 0 : s[t - 1];
  if (t < nb) bsum[t] = excl;
}

__global__ void writeptr_k(const int* __restrict__ deg, const int* __restrict__ bsum,
                           int* __restrict__ rowptr, int* __restrict__ cursor, int N, int E) {
  __shared__ int s[256];
  int t = threadIdx.x;
  int i = blockIdx.x * 256 + t;
  s[t] = (i < N) ? deg[i] : 0;
  __syncthreads();
  for (int off = 1; off < 256; off <<= 1) {
    int v = (t >= off) ? s[t - off] : 0;
    __syncthreads();
    if (t >= off) s[t] += v;
    __syncthreads();
  }
  int excl = bsum[blockIdx.x] + ((t == 0) ? 0 : s[t - 1]);
  if (i < N) {
    rowptr[i] = excl;
    cursor[i] = excl;
  }
  if (i == N - 1) rowptr[N] = E;
}

__global__ void fill_k(const int* __restrict__ src, const int* __restrict__ dst,
                       const float* __restrict__ eattr, int* __restrict__ cursor,
                       int* __restrict__ srcs_s, float4* __restrict__ ea4, int E) {
  int e = blockIdx.x * 256 + threadIdx.x;
  if (e >= E) return;
  int d = dst[e];
  int pos = atomicAdd(&cursor[d], 1);
  srcs_s[pos] = src[e];
  ea4[pos] = make_float4(eattr[e * 3 + 0], eattr[e * 3 + 1], eattr[e * 3 + 2], 0.0f);
}

// ---------------- fused dual node linear, transposed-LDS --------------------
// out{1,2}[n,j] = sum_k X[n,k]*W{1,2}[j,k] + b{1,2}[j], K=128 fixed.
// Thread tile: 4 rows x 4 cols x 2 weight sets.  Inner loop: 3x ds_read_b128.
template <int J>
__global__ __launch_bounds__(256, 3) void node_linear2t_k(
    const float* __restrict__ X,
    const float* __restrict__ W1, const float* __restrict__ b1v,
    const float* __restrict__ W2, const float* __restrict__ b2v,
    float* __restrict__ out1, float* __restrict__ out2, int nrows) {
  constexpr int K = 128, KB = 32;
  constexpr int JG = J / 4;      // col groups (32 or 16)
  constexpr int RG = 256 / JG;   // row groups (8 or 16)
  constexpr int RB = RG * 4;     // rows per block (32 or 64)
  constexpr int XP = RB + 4;     // pad keeps 16B alignment (RB%4==0)
  constexpr int WP = J + 4;
  __shared__ float sXT[K][XP];
  __shared__ float sW1T[KB][WP];
  __shared__ float sW2T[KB][WP];

  int tid = threadIdx.x;
  int n0 = blockIdx.x * RB;

  // ---- stage X transposed: lanes vary r (conflict-free LDS writes) ----
  {
    int r = tid & (RB - 1);
    int kq0 = tid / RB;              // 0..(256/RB-1)
    constexpr int KQS = 256 / RB;    // 8 or 4
    int n = n0 + r;
    bool ok = n < nrows;
    for (int kq = kq0; kq < K / 4; kq += KQS) {
      float4 v = ok ? *(const float4*)&X[(size_t)n * K + kq * 4]
                    : make_float4(0.f, 0.f, 0.f, 0.f);
      sXT[kq * 4 + 0][r] = v.x;
      sXT[kq * 4 + 1][r] = v.y;
      sXT[kq * 4 + 2][r] = v.z;
      sXT[kq * 4 + 3][r] = v.w;
    }
  }

  int jg = tid % JG;
  int rg = tid / JG;
  float acc1[4][4] = {}, acc2[4][4] = {};

  for (int kb = 0; kb < K / KB; ++kb) {
    __syncthreads();
    // ---- stage W chunk transposed: lanes vary j (conflict-free writes) ----
    {
      int j = tid & (J - 1);
      int kq0 = tid / J;             // 0..(256/J-1)
      constexpr int KQS = 256 / J;   // 2 or 4
      for (int kq = kq0; kq < KB / 4; kq += KQS) {
        float4 v1 = *(const float4*)&W1[(size_t)j * K + kb * KB + kq * 4];
        float4 v2 = *(const float4*)&W2[(size_t)j * K + kb * KB + kq * 4];
        sW1T[kq * 4 + 0][j] = v1.x;
        sW1T[kq * 4 + 1][j] = v1.y;
        sW1T[kq * 4 + 2][j] = v1.z;
        sW1T[kq * 4 + 3][j] = v1.w;
        sW2T[kq * 4 + 0][j] = v2.x;
        sW2T[kq * 4 + 1][j] = v2.y;
        sW2T[kq * 4 + 2][j] = v2.z;
        sW2T[kq * 4 + 3][j] = v2.w;
      }
    }
    __syncthreads();
#pragma unroll
    for (int k = 0; k < KB; ++k) {
      float4 xv = *(const float4*)&sXT[kb * KB + k][rg * 4];
      float4 w1 = *(const float4*)&sW1T[k][jg * 4];
      float4 w2 = *(const float4*)&sW2T[k][jg * 4];
      float xs[4] = {xv.x, xv.y, xv.z, xv.w};
      float w1s[4] = {w1.x, w1.y, w1.z, w1.w};
      float w2s[4] = {w2.x, w2.y, w2.z, w2.w};
#pragma unroll
      for (int i = 0; i < 4; ++i)
#pragma unroll
        for (int q = 0; q < 4; ++q) {
          acc1[i][q] = fmaf(xs[i], w1s[q], acc1[i][q]);
          acc2[i][q] = fmaf(xs[i], w2s[q], acc2[i][q]);
        }
    }
  }

  float4 bv1 = *(const float4*)&b1v[jg * 4];
  float4 bv2 = *(const float4*)&b2v[jg * 4];
#pragma unroll
  for (int i = 0; i < 4; ++i) {
    int n = n0 + rg * 4 + i;
    if (n < nrows) {
      float4 o1 = make_float4(acc1[i][0] + bv1.x, acc1[i][1] + bv1.y,
                              acc1[i][2] + bv1.z, acc1[i][3] + bv1.w);
      float4 o2 = make_float4(acc2[i][0] + bv2.x, acc2[i][1] + bv2.y,
                              acc2[i][2] + bv2.z, acc2[i][3] + bv2.w);
      *(float4*)&out1[(size_t)n * J + jg * 4] = o1;
      *(float4*)&out2[(size_t)n * J + jg * 4] = o2;
    }
  }
}

// ---------------- fused GATv2 layer 1 (H=4, C=32, concat) -------------------
__global__ __launch_bounds__(256, 2) void gat1_fused_k(
    const int* __restrict__ rowptr, const int* __restrict__ srcs,
    const float4* __restrict__ ea4, const float* __restrict__ xl,
    const float* __restrict__ xr, const float* __restrict__ We,
    const float* __restrict__ att, const float* __restrict__ bias,
    float* __restrict__ out, int N) {
  __shared__ __align__(16) float rows[16 * 132];
  __shared__ float sex[16 * 5];
  __shared__ float comb[4 * 64 * 3];
  __shared__ float comb_es[4 * 4];

  int tid = threadIdx.x;
  int wv = tid >> 6, lane = tid & 63;
  int n = blockIdx.x;
  int e4 = lane >> 4;
  int r = lane & 15;
  int cA = r * 8;
  int h = r >> 2;
  int hL = lane >> 4;
  int eslot = wv * 4 + e4;

  float4 wreg[8];
  float xrA[8];
#pragma unroll
  for (int i = 0; i < 8; ++i) {
    int c = cA + i;
    wreg[i] = make_float4(We[c * 3], We[c * 3 + 1], We[c * 3 + 2], att[c]);
    xrA[i] = xr[(size_t)n * 128 + c];
  }
  int beg = rowptr[n], end = rowptr[n + 1];

  float acc0 = 0.f, acc1 = 0.f, den = 0.f;
  float es0 = 0.f, es1 = 0.f, es2 = 0.f;

  for (int base = beg; base < end; base += 16) {
    int gi = base + eslot;
    bool valid = gi < end;
    int s = valid ? srcs[gi] : 0;
    float4 ea = valid ? ea4[gi] : make_float4(0.f, 0.f, 0.f, 0.f);
    float4 r0 = make_float4(0.f, 0.f, 0.f, 0.f), r1 = r0;
    if (valid) {
      const float4* rp = (const float4*)&xl[(size_t)s * 128 + cA];
      r0 = rp[0];
      r1 = rp[1];
    }
    if (r == 0 && valid) { es0 += ea.x; es1 += ea.y; es2 += ea.z; }
    *(float4*)&rows[eslot * 132 + cA] = r0;
    *(float4*)&rows[eslot * 132 + cA + 4] = r1;
    float v = 0.f;
#pragma unroll
    for (int q = 0; q < 8; ++q) {
      float xv = (q == 0) ? r0.x : (q == 1) ? r0.y : (q == 2) ? r0.z : (q == 3) ? r0.w
               : (q == 4) ? r1.x : (q == 5) ? r1.y : (q == 6) ? r1.z : r1.w;
      float4 w = wreg[q];
      float m = xv + xrA[q] + ea.x * w.x + ea.y * w.y + ea.z * w.z;
      m = fmaxf(m, 0.2f * m);
      v = fmaf(m, w.w, v);
    }
    v += __shfl_xor(v, 1);
    v += __shfl_xor(v, 2);
    float ex = valid ? __expf(v) : 0.f;
    if ((r & 3) == 0) sex[eslot * 5 + h] = ex;
    wbar();
#pragma unroll
    for (int j = 0; j < 4; ++j) {
      int sl = wv * 4 + j;
      float exj = sex[sl * 5 + hL];
      float2 xlv = *(const float2*)&rows[sl * 132 + 2 * lane];
      acc0 = fmaf(exj, xlv.x, acc0);
      acc1 = fmaf(exj, xlv.y, acc1);
      den += exj;
    }
    wbar();
  }

  es0 += __shfl_xor(es0, 16); es0 += __shfl_xor(es0, 32);
  es1 += __shfl_xor(es1, 16); es1 += __shfl_xor(es1, 32);
  es2 += __shfl_xor(es2, 16); es2 += __shfl_xor(es2, 32);
  if (lane == 0) {
    comb_es[wv * 4 + 0] = es0;
    comb_es[wv * 4 + 1] = es1;
    comb_es[wv * 4 + 2] = es2;
  }
  float* cb = &comb[(wv * 64 + lane) * 3];
  cb[0] = acc0; cb[1] = acc1; cb[2] = den;
  __syncthreads();
  if (wv != 0) return;

  acc0 = 0.f; acc1 = 0.f; den = 0.f;
#pragma unroll
  for (int w = 0; w < 4; ++w) {
    const float* cw = &comb[(w * 64 + lane) * 3];
    acc0 += cw[0]; acc1 += cw[1]; den += cw[2];
  }
  float et0 = comb_es[0] + comb_es[4] + comb_es[8] + comb_es[12];
  float et1 = comb_es[1] + comb_es[5] + comb_es[9] + comb_es[13];
  float et2 = comb_es[2] + comb_es[6] + comb_es[10] + comb_es[14];
  float inv = 1.0f / fmaxf((float)(end - beg), 1.0f);
  et0 *= inv; et1 *= inv; et2 *= inv;

  int c0 = 2 * lane;
  float2 xls = *(const float2*)&xl[(size_t)n * 128 + c0];
  float2 xrv = *(const float2*)&xr[(size_t)n * 128 + c0];
  float m0 = xls.x + xrv.x + et0 * We[c0 * 3] + et1 * We[c0 * 3 + 1] + et2 * We[c0 * 3 + 2];
  m0 = fmaxf(m0, 0.2f * m0);
  float m1 = xls.y + xrv.y + et0 * We[c0 * 3 + 3] + et1 * We[c0 * 3 + 4] + et2 * We[c0 * 3 + 5];
  m1 = fmaxf(m1, 0.2f * m1);
  float t = m0 * att[c0] + m1 * att[c0 + 1];
#pragma unroll
  for (int off = 1; off < 16; off <<= 1) t += __shfl_xor(t, off);
  float ex = __expf(t);
  den += ex;
  acc0 = fmaf(ex, xls.x, acc0);
  acc1 = fmaf(ex, xls.y, acc1);

  float o0 = acc0 / den + bias[c0];
  float o1 = acc1 / den + bias[c0 + 1];
  o0 = o0 > 0.f ? o0 : __expf(o0) - 1.0f;
  o1 = o1 > 0.f ? o1 : __expf(o1) - 1.0f;
  *(float2*)&out[(size_t)n * 128 + c0] = make_float2(o0, o1);
}

// ---------------- fused GATv2 layer 2 (H=1, C=64, mean) ---------------------
__global__ __launch_bounds__(256, 2) void gat2_fused_k(
    const int* __restrict__ rowptr, const int* __restrict__ srcs,
    const float4* __restrict__ ea4, const float* __restrict__ xl,
    const float* __restrict__ xr, const float* __restrict__ We,
    const float* __restrict__ att, const float* __restrict__ bias,
    float* __restrict__ out, int N) {
  __shared__ __align__(16) float rows[16 * 68];
  __shared__ float sex[16];
  __shared__ float comb[4 * 64 * 2];
  __shared__ float comb_es[4 * 4];

  int tid = threadIdx.x;
  int wv = tid >> 6, lane = tid & 63;
  int n = blockIdx.x;
  int e4 = lane >> 4;
  int r = lane & 15;
  int cA = r * 4;
  int eslot = wv * 4 + e4;

  float4 wreg[4];
  float xrA[4];
#pragma unroll
  for (int i = 0; i < 4; ++i) {
    int c = cA + i;
    wreg[i] = make_float4(We[c * 3], We[c * 3 + 1], We[c * 3 + 2], att[c]);
    xrA[i] = xr[(size_t)n * 64 + c];
  }
  int beg = rowptr[n], end = rowptr[n + 1];

  float acc = 0.f, den = 0.f;
  float es0 = 0.f, es1 = 0.f, es2 = 0.f;

  for (int base = beg; base < end; base += 16) {
    int gi = base + eslot;
    bool valid = gi < end;
    int s = valid ? srcs[gi] : 0;
    float4 ea = valid ? ea4[gi] : make_float4(0.f, 0.f, 0.f, 0.f);
    float4 r0 = make_float4(0.f, 0.f, 0.f, 0.f);
    if (valid) r0 = *(const float4*)&xl[(size_t)s * 64 + cA];
    if (r == 0 && valid) { es0 += ea.x; es1 += ea.y; es2 += ea.z; }
    *(float4*)&rows[eslot * 68 + cA] = r0;
    float v = 0.f;
#pragma unroll
    for (int q = 0; q < 4; ++q) {
      float xv = (q == 0) ? r0.x : (q == 1) ? r0.y : (q == 2) ? r0.z : r0.w;
      float4 w = wreg[q];
      float m = xv + xrA[q] + ea.x * w.x + ea.y * w.y + ea.z * w.z;
      m = fmaxf(m, 0.2f * m);
      v = fmaf(m, w.w, v);
    }
    v += __shfl_xor(v, 1);
    v += __shfl_xor(v, 2);
    v += __shfl_xor(v, 4);
    v += __shfl_xor(v, 8);
    float ex = valid ? __expf(v) : 0.f;
    if (r == 0) sex[eslot] = ex;
    wbar();
#pragma unroll
    for (int j = 0; j < 4; ++j) {
      int sl = wv * 4 + j;
      float exj = sex[sl];
      acc = fmaf(exj, rows[sl * 68 + lane], acc);
      den += exj;
    }
    wbar();
  }

  es0 += __shfl_xor(es0, 16); es0 += __shfl_xor(es0, 32);
  es1 += __shfl_xor(es1, 16); es1 += __shfl_xor(es1, 32);
  es2 += __shfl_xor(es2, 16); es2 += __shfl_xor(es2, 32);
  if (lane == 0) {
    comb_es[wv * 4 + 0] = es0;
    comb_es[wv * 4 + 1] = es1;
    comb_es[wv * 4 + 2] = es2;
  }
  float* cb = &comb[(wv * 64 + lane) * 2];
  cb[0] = acc; cb[1] = den;
  __syncthreads();
  if (wv != 0) return;

  acc = 0.f; den = 0.f;
#pragma unroll
  for (int w = 0; w < 4; ++w) {
    const float* cw = &comb[(w * 64 + lane) * 2];
    acc += cw[0]; den += cw[1];
  }
  float et0 = comb_es[0] + comb_es[4] + comb_es[8] + comb_es[12];
  float et1 = comb_es[1] + comb_es[5] + comb_es[9] + comb_es[13];
  float et2 = comb_es[2] + comb_es[6] + comb_es[10] + comb_es[14];
  float inv = 1.0f / fmaxf((float)(end - beg), 1.0f);
  et0 *= inv; et1 *= inv; et2 *= inv;

  float xls = xl[(size_t)n * 64 + lane];
  float xrv = xr[(size_t)n * 64 + lane];
  float m = xls + xrv + et0 * We[lane * 3] + et1 * We[lane * 3 + 1] + et2 * We[lane * 3 + 2];
  m = fmaxf(m, 0.2f * m);
  float t = m * att[lane];
#pragma unroll
  for (int off = 1; off < 64; off <<= 1) t += __shfl_xor(t, off);
  float ex = __expf(t);
  den += ex;
  acc = fmaf(ex, xls, acc);

  float o = acc / den + bias[lane];
  o = o > 0.f ? o : __expf(o) - 1.0f;
  out[(size_t)n * 64 + lane] = o;
}

// ---------------- mean pool over batch --------------------------------------
__global__ void pool_k(const float* __restrict__ h2, const int* __restrict__ batch,
                       float* __restrict__ pooled, float* __restrict__ cntg, int N) {
  long t = (long)blockIdx.x * blockDim.x + threadIdx.x;
  int n = (int)(t >> 6);
  int c = (int)(t & 63);
  if (n >= N) return;
  int g = batch[n];
  atomicAdd(&pooled[(size_t)g * 64 + c], h2[(size_t)n * 64 + c]);
  if (c == 0) atomicAdd(&cntg[g], 1.0f);
}

// ---------------- final MLP head --------------------------------------------
__global__ void final_mlp_k(const float* __restrict__ pooled, const float* __restrict__ cntg,
                            const float* __restrict__ u, const float* __restrict__ W1,
                            const float* __restrict__ b1, const float* __restrict__ Wh,
                            const float* __restrict__ bh, float* __restrict__ out) {
  __shared__ float feat[65];
  __shared__ float z[32];
  int g = blockIdx.x;
  int t = threadIdx.x;
  float inv = 1.0f / fmaxf(cntg[g], 1.0f);
  feat[t] = pooled[(size_t)g * 64 + t] * inv;
  if (t == 0) feat[64] = u[g];
  __syncthreads();
  if (t < 32) {
    float a = b1[t];
    for (int k = 0; k < 65; ++k) a += feat[k] * W1[t * 65 + k];
    z[t] = fmaxf(a, 0.0f);
  }
  __syncthreads();
  if (t < 10) {
    float a = bh[t];
    for (int k = 0; k < 32; ++k) a += z[k] * Wh[t * 32 + k];
    out[g * 10 + t] = a;
  }
}

// ---------------------------------------------------------------------------
extern "C" void kernel_launch(void* const* d_in, const int* in_sizes, int n_in,
                              void* d_out, int out_size, void* d_ws, size_t ws_size,
                              hipStream_t stream) {
  const float* x      = (const float*)d_in[0];
  const int*   eidx   = (const int*)d_in[1];
  const float* eattr  = (const float*)d_in[2];
  const int*   batch  = (const int*)d_in[3];
  const float* u      = (const float*)d_in[4];
  const float* Wl1    = (const float*)d_in[5];
  const float* bl1    = (const float*)d_in[6];
  const float* Wr1    = (const float*)d_in[7];
  const float* br1    = (const float*)d_in[8];
  const float* We1    = (const float*)d_in[9];
  const float* att1   = (const float*)d_in[10];
  const float* b1     = (const float*)d_in[11];
  const float* Wl2    = (const float*)d_in[12];
  const float* bl2    = (const float*)d_in[13];
  const float* Wr2    = (const float*)d_in[14];
  const float* br2    = (const float*)d_in[15];
  const float* We2    = (const float*)d_in[16];
  const float* att2   = (const float*)d_in[17];
  const float* b2     = (const float*)d_in[18];
  const float* W_lin1 = (const float*)d_in[19];
  const float* b_lin1 = (const float*)d_in[20];
  const float* W_head = (const float*)d_in[21];
  const float* b_head = (const float*)d_in[22];

  const int N = in_sizes[0] / 128;
  const int E = in_sizes[1] / 2;
  const int G = in_sizes[4];
  const int* srcp = eidx;
  const int* dstp = eidx + E;

  // ---- workspace layout ----
  float* buf1 = (float*)d_ws;                       // xl1 (N*128) -> xl2 (N*64)
  float* buf2 = buf1 + (size_t)N * 128;             // xr1 (N*128) -> xr2 (N*64)
  float* buf3 = buf2 + (size_t)N * 128;             // h1  (N*128) -> h2  (N*64)
  float4* ea4 = (float4*)(buf3 + (size_t)N * 128);  // E sorted edge attrs
  int* srcs_s = (int*)(ea4 + E);                    // E sorted src ids
  int* deg    = srcs_s + E;                         // N
  int* rowptr = deg + N;                            // N+1
  int* cursor = rowptr + N + 1;                     // N
  int* bsum   = cursor + N;                         // 256
  float* pooled = (float*)(bsum + 256);             // G*64
  float* pcnt   = pooled + (size_t)G * 64;          // G

  const int nb = (N + 255) / 256;

  // ---- CSR build (sort edges by dst) ----
  hipMemsetAsync(deg, 0, sizeof(int) * (size_t)N, stream);
  hist_k<<<(E + 255) / 256, 256, 0, stream>>>(dstp, deg, E);
  blocksum_k<<<nb, 256, 0, stream>>>(deg, bsum, N);
  scan_bsum_k<<<1, 256, 0, stream>>>(bsum, nb);
  writeptr_k<<<nb, 256, 0, stream>>>(deg, bsum, rowptr, cursor, N, E);
  fill_k<<<(E + 255) / 256, 256, 0, stream>>>(srcp, dstp, eattr, cursor, srcs_s, ea4, E);

  // ---- layer 1 ----
  node_linear2t_k<128><<<(N + 31) / 32, 256, 0, stream>>>(x, Wl1, bl1, Wr1, br1,
                                                          buf1, buf2, N);
  gat1_fused_k<<<N, 256, 0, stream>>>(rowptr, srcs_s, ea4, buf1, buf2,
                                      We1, att1, b1, buf3, N);

  // ---- layer 2 ----
  node_linear2t_k<64><<<(N + 63) / 64, 256, 0, stream>>>(buf3, Wl2, bl2, Wr2, br2,
                                                         buf1, buf2, N);
  gat2_fused_k<<<N, 256, 0, stream>>>(rowptr, srcs_s, ea4, buf1, buf2,
                                      We2, att2, b2, buf3, N);

  // ---- pool + head ----
  hipMemsetAsync(pooled, 0, sizeof(float) * ((size_t)G * 64 + G), stream);
  pool_k<<<((long)N * 64 + 255) / 256, 256, 0, stream>>>(buf3, batch, pooled, pcnt, N);
  final_mlp_k<<<G, 64, 0, stream>>>(pooled, pcnt, u, W_lin1, b_lin1, W_head, b_head,
                                    (float*)d_out);
}

// Round 7
// 568.472 us; speedup vs baseline: 1.3100x; 1.0762x over previous
//
#include <hip/hip_runtime.h>
#include <math.h>

// ---------------------------------------------------------------------------
// TacticalGAT round 7: wave-per-node GAT with lane=channel mapping -- per edge
// one fully-coalesced row load, score partial per lane, 4-level (gat1) /
// 6-level (gat2) shfl reduce, aggregation from the same registers.  No LDS,
// no barriers, no bank conflicts (r6: 4.6M conflict cycles + LDS round-trip).
// Wave-uniform srcs/ea via readfirstlane -> scalar loads; 2-deep pipeline.
// Pool atomics replaced by sorted-batch boundaries + fused pool/MLP head.
// ---------------------------------------------------------------------------

// ---------------- CSR build -------------------------------------------------
__global__ void hist_k(const int* __restrict__ dst, int* __restrict__ deg, int E) {
  int e = blockIdx.x * 256 + threadIdx.x;
  if (e < E) atomicAdd(&deg[dst[e]], 1);
}

__global__ void blocksum_k(const int* __restrict__ deg, int* __restrict__ bsum, int N) {
  __shared__ int s[256];
  int i = blockIdx.x * 256 + threadIdx.x;
  s[threadIdx.x] = (i < N) ? deg[i] : 0;
  __syncthreads();
  for (int off = 128; off; off >>= 1) {
    if (threadIdx.x < off) s[threadIdx.x] += s[threadIdx.x + off];
    __syncthreads();
  }
  if (threadIdx.x == 0) bsum[blockIdx.x] = s[0];
}

__global__ void scan_bsum_k(int* __restrict__ bsum, int nb) {
  __shared__ int s[256];
  int t = threadIdx.x;
  s[t] = (t < nb) ? bsum[t] : 0;
  __syncthreads();
  for (int off = 1; off < 256; off <<= 1) {
    int v = (t >= off) ? s[t - off] : 0;
    __syncthreads();
    if (t >= off) s[t] += v;
    __syncthreads();
  }
  int excl = (t == 0) ? 0 : s[t - 1];
  if (t < nb) bsum[t] = excl;
}

__global__ void writeptr_k(const int* __restrict__ deg, const int* __restrict__ bsum,
                           int* __restrict__ rowptr, int* __restrict__ cursor, int N, int E) {
  __shared__ int s[256];
  int t = threadIdx.x;
  int i = blockIdx.x * 256 + t;
  s[t] = (i < N) ? deg[i] : 0;
  __syncthreads();
  for (int off = 1; off < 256; off <<= 1) {
    int v = (t >= off) ? s[t - off] : 0;
    __syncthreads();
    if (t >= off) s[t] += v;
    __syncthreads();
  }
  int excl = bsum[blockIdx.x] + ((t == 0) ? 0 : s[t - 1]);
  if (i < N) {
    rowptr[i] = excl;
    cursor[i] = excl;
  }
  if (i == N - 1) rowptr[N] = E;
}

__global__ void fill_k(const int* __restrict__ src, const int* __restrict__ dst,
                       const float* __restrict__ eattr, int* __restrict__ cursor,
                       int* __restrict__ srcs_s, float4* __restrict__ ea4, int E) {
  int e = blockIdx.x * 256 + threadIdx.x;
  if (e >= E) return;
  int d = dst[e];
  int pos = atomicAdd(&cursor[d], 1);
  srcs_s[pos] = src[e];
  ea4[pos] = make_float4(eattr[e * 3 + 0], eattr[e * 3 + 1], eattr[e * 3 + 2], 0.0f);
}

// ---------------- fused dual node linear, transposed-LDS --------------------
template <int J>
__global__ __launch_bounds__(256, 3) void node_linear2t_k(
    const float* __restrict__ X,
    const float* __restrict__ W1, const float* __restrict__ b1v,
    const float* __restrict__ W2, const float* __restrict__ b2v,
    float* __restrict__ out1, float* __restrict__ out2, int nrows) {
  constexpr int K = 128, KB = 32;
  constexpr int JG = J / 4;
  constexpr int RG = 256 / JG;
  constexpr int RB = RG * 4;
  constexpr int XP = RB + 4;
  constexpr int WP = J + 4;
  __shared__ float sXT[K][XP];
  __shared__ float sW1T[KB][WP];
  __shared__ float sW2T[KB][WP];

  int tid = threadIdx.x;
  int n0 = blockIdx.x * RB;

  {
    int r = tid & (RB - 1);
    int kq0 = tid / RB;
    constexpr int KQS = 256 / RB;
    int n = n0 + r;
    bool ok = n < nrows;
    for (int kq = kq0; kq < K / 4; kq += KQS) {
      float4 v = ok ? *(const float4*)&X[(size_t)n * K + kq * 4]
                    : make_float4(0.f, 0.f, 0.f, 0.f);
      sXT[kq * 4 + 0][r] = v.x;
      sXT[kq * 4 + 1][r] = v.y;
      sXT[kq * 4 + 2][r] = v.z;
      sXT[kq * 4 + 3][r] = v.w;
    }
  }

  int jg = tid % JG;
  int rg = tid / JG;
  float acc1[4][4] = {}, acc2[4][4] = {};

  for (int kb = 0; kb < K / KB; ++kb) {
    __syncthreads();
    {
      int j = tid & (J - 1);
      int kq0 = tid / J;
      constexpr int KQS = 256 / J;
      for (int kq = kq0; kq < KB / 4; kq += KQS) {
        float4 v1 = *(const float4*)&W1[(size_t)j * K + kb * KB + kq * 4];
        float4 v2 = *(const float4*)&W2[(size_t)j * K + kb * KB + kq * 4];
        sW1T[kq * 4 + 0][j] = v1.x;
        sW1T[kq * 4 + 1][j] = v1.y;
        sW1T[kq * 4 + 2][j] = v1.z;
        sW1T[kq * 4 + 3][j] = v1.w;
        sW2T[kq * 4 + 0][j] = v2.x;
        sW2T[kq * 4 + 1][j] = v2.y;
        sW2T[kq * 4 + 2][j] = v2.z;
        sW2T[kq * 4 + 3][j] = v2.w;
      }
    }
    __syncthreads();
#pragma unroll
    for (int k = 0; k < KB; ++k) {
      float4 xv = *(const float4*)&sXT[kb * KB + k][rg * 4];
      float4 w1 = *(const float4*)&sW1T[k][jg * 4];
      float4 w2 = *(const float4*)&sW2T[k][jg * 4];
      float xs[4] = {xv.x, xv.y, xv.z, xv.w};
      float w1s[4] = {w1.x, w1.y, w1.z, w1.w};
      float w2s[4] = {w2.x, w2.y, w2.z, w2.w};
#pragma unroll
      for (int i = 0; i < 4; ++i)
#pragma unroll
        for (int q = 0; q < 4; ++q) {
          acc1[i][q] = fmaf(xs[i], w1s[q], acc1[i][q]);
          acc2[i][q] = fmaf(xs[i], w2s[q], acc2[i][q]);
        }
    }
  }

  float4 bv1 = *(const float4*)&b1v[jg * 4];
  float4 bv2 = *(const float4*)&b2v[jg * 4];
#pragma unroll
  for (int i = 0; i < 4; ++i) {
    int n = n0 + rg * 4 + i;
    if (n < nrows) {
      float4 o1 = make_float4(acc1[i][0] + bv1.x, acc1[i][1] + bv1.y,
                              acc1[i][2] + bv1.z, acc1[i][3] + bv1.w);
      float4 o2 = make_float4(acc2[i][0] + bv2.x, acc2[i][1] + bv2.y,
                              acc2[i][2] + bv2.z, acc2[i][3] + bv2.w);
      *(float4*)&out1[(size_t)n * J + jg * 4] = o1;
      *(float4*)&out2[(size_t)n * J + jg * 4] = o2;
    }
  }
}

// ---------------- fused GATv2 layer 1 (H=4, C=32, concat) -------------------
// wave per node, lane = channel pair c0=2*lane; per edge one coalesced 512B
// row load; 4-level shfl reduce within 16-lane head group; agg from regs.
__global__ __launch_bounds__(256) void gat1_fused_k(
    const int* __restrict__ rowptr, const int* __restrict__ srcs,
    const float4* __restrict__ ea4, const float* __restrict__ xl,
    const float* __restrict__ xr, const float* __restrict__ We,
    const float* __restrict__ att, const float* __restrict__ bias,
    float* __restrict__ out, int N) {
  constexpr int CH = 8;
  int lane = threadIdx.x & 63;
  int n = __builtin_amdgcn_readfirstlane((int)((blockIdx.x * 256 + threadIdx.x) >> 6));
  if (n >= N) return;
  int c0 = 2 * lane;
  float4 w0 = make_float4(We[c0 * 3], We[c0 * 3 + 1], We[c0 * 3 + 2], att[c0]);
  float4 w1 = make_float4(We[c0 * 3 + 3], We[c0 * 3 + 4], We[c0 * 3 + 5], att[c0 + 1]);
  float2 xrv = *(const float2*)&xr[(size_t)n * 128 + c0];
  int beg = rowptr[n], end = rowptr[n + 1];

  float acc0 = 0.f, acc1 = 0.f, den = 0.f;
  float es0 = 0.f, es1 = 0.f, es2 = 0.f;

  float2 rA[CH], rB[CH];
  float4 eaA[CH], eaB[CH];
  int sN[CH];

  // prologue: chunk0 rows+ea inline; chunk1 meta into sN
#pragma unroll
  for (int j = 0; j < CH; ++j)
    if (beg + j < end) {
      int s = srcs[beg + j];
      rA[j] = *(const float2*)&xl[(size_t)s * 128 + c0];
      eaA[j] = ea4[beg + j];
    }
#pragma unroll
  for (int j = 0; j < CH; ++j)
    if (beg + CH + j < end) sN[j] = srcs[beg + CH + j];

  auto compute = [&](int base, float2* r, float4* ea) {
#pragma unroll
    for (int j = 0; j < CH; ++j)
      if (base + j < end) {
        float4 e = ea[j];
        es0 += e.x; es1 += e.y; es2 += e.z;
        float m0 = r[j].x + xrv.x + e.x * w0.x + e.y * w0.y + e.z * w0.z;
        float m1 = r[j].y + xrv.y + e.x * w1.x + e.y * w1.y + e.z * w1.z;
        m0 = fmaxf(m0, 0.2f * m0);
        m1 = fmaxf(m1, 0.2f * m1);
        float v = fmaf(m0, w0.w, m1 * w1.w);
        v += __shfl_xor(v, 1);
        v += __shfl_xor(v, 2);
        v += __shfl_xor(v, 4);
        v += __shfl_xor(v, 8);
        float ex = __expf(v);
        den += ex;
        acc0 = fmaf(ex, r[j].x, acc0);
        acc1 = fmaf(ex, r[j].y, acc1);
      }
  };

  int base = beg;
  while (true) {
    {  // current = A
      int nb = base + CH;
      if (nb < end) {
#pragma unroll
        for (int j = 0; j < CH; ++j)
          if (nb + j < end) {
            rB[j] = *(const float2*)&xl[(size_t)sN[j] * 128 + c0];
            eaB[j] = ea4[nb + j];
          }
#pragma unroll
        for (int j = 0; j < CH; ++j)
          if (nb + CH + j < end) sN[j] = srcs[nb + CH + j];
      }
      compute(base, rA, eaA);
      base = nb;
      if (base >= end) break;
    }
    {  // current = B
      int nb = base + CH;
      if (nb < end) {
#pragma unroll
        for (int j = 0; j < CH; ++j)
          if (nb + j < end) {
            rA[j] = *(const float2*)&xl[(size_t)sN[j] * 128 + c0];
            eaA[j] = ea4[nb + j];
          }
#pragma unroll
        for (int j = 0; j < CH; ++j)
          if (nb + CH + j < end) sN[j] = srcs[nb + CH + j];
      }
      compute(base, rB, eaB);
      base = nb;
      if (base >= end) break;
    }
  }

  // self loop (attr = mean of incoming)
  float invd = 1.0f / fmaxf((float)(end - beg), 1.0f);
  es0 *= invd; es1 *= invd; es2 *= invd;
  float2 xls = *(const float2*)&xl[(size_t)n * 128 + c0];
  float m0 = xls.x + xrv.x + es0 * w0.x + es1 * w0.y + es2 * w0.z;
  float m1 = xls.y + xrv.y + es0 * w1.x + es1 * w1.y + es2 * w1.z;
  m0 = fmaxf(m0, 0.2f * m0);
  m1 = fmaxf(m1, 0.2f * m1);
  float v = fmaf(m0, w0.w, m1 * w1.w);
  v += __shfl_xor(v, 1);
  v += __shfl_xor(v, 2);
  v += __shfl_xor(v, 4);
  v += __shfl_xor(v, 8);
  float ex = __expf(v);
  den += ex;
  acc0 = fmaf(ex, xls.x, acc0);
  acc1 = fmaf(ex, xls.y, acc1);

  float o0 = acc0 / den + bias[c0];
  float o1 = acc1 / den + bias[c0 + 1];
  o0 = o0 > 0.f ? o0 : __expf(o0) - 1.0f;  // ELU
  o1 = o1 > 0.f ? o1 : __expf(o1) - 1.0f;
  *(float2*)&out[(size_t)n * 128 + c0] = make_float2(o0, o1);
}

// ---------------- fused GATv2 layer 2 (H=1, C=64, mean) ---------------------
__global__ __launch_bounds__(256) void gat2_fused_k(
    const int* __restrict__ rowptr, const int* __restrict__ srcs,
    const float4* __restrict__ ea4, const float* __restrict__ xl,
    const float* __restrict__ xr, const float* __restrict__ We,
    const float* __restrict__ att, const float* __restrict__ bias,
    float* __restrict__ out, int N) {
  constexpr int CH = 8;
  int lane = threadIdx.x & 63;
  int n = __builtin_amdgcn_readfirstlane((int)((blockIdx.x * 256 + threadIdx.x) >> 6));
  if (n >= N) return;
  float4 w = make_float4(We[lane * 3], We[lane * 3 + 1], We[lane * 3 + 2], att[lane]);
  float xrv = xr[(size_t)n * 64 + lane];
  int beg = rowptr[n], end = rowptr[n + 1];

  float acc = 0.f, den = 0.f;
  float es0 = 0.f, es1 = 0.f, es2 = 0.f;

  float rA[CH], rB[CH];
  float4 eaA[CH], eaB[CH];
  int sN[CH];

#pragma unroll
  for (int j = 0; j < CH; ++j)
    if (beg + j < end) {
      int s = srcs[beg + j];
      rA[j] = xl[(size_t)s * 64 + lane];
      eaA[j] = ea4[beg + j];
    }
#pragma unroll
  for (int j = 0; j < CH; ++j)
    if (beg + CH + j < end) sN[j] = srcs[beg + CH + j];

  auto compute = [&](int base, float* r, float4* ea) {
#pragma unroll
    for (int j = 0; j < CH; ++j)
      if (base + j < end) {
        float4 e = ea[j];
        es0 += e.x; es1 += e.y; es2 += e.z;
        float m = r[j] + xrv + e.x * w.x + e.y * w.y + e.z * w.z;
        m = fmaxf(m, 0.2f * m);
        float v = m * w.w;
        v += __shfl_xor(v, 1);
        v += __shfl_xor(v, 2);
        v += __shfl_xor(v, 4);
        v += __shfl_xor(v, 8);
        v += __shfl_xor(v, 16);
        v += __shfl_xor(v, 32);
        float ex = __expf(v);
        den += ex;
        acc = fmaf(ex, r[j], acc);
      }
  };

  int base = beg;
  while (true) {
    {
      int nb = base + CH;
      if (nb < end) {
#pragma unroll
        for (int j = 0; j < CH; ++j)
          if (nb + j < end) {
            rB[j] = xl[(size_t)sN[j] * 64 + lane];
            eaB[j] = ea4[nb + j];
          }
#pragma unroll
        for (int j = 0; j < CH; ++j)
          if (nb + CH + j < end) sN[j] = srcs[nb + CH + j];
      }
      compute(base, rA, eaA);
      base = nb;
      if (base >= end) break;
    }
    {
      int nb = base + CH;
      if (nb < end) {
#pragma unroll
        for (int j = 0; j < CH; ++j)
          if (nb + j < end) {
            rA[j] = xl[(size_t)sN[j] * 64 + lane];
            eaA[j] = ea4[nb + j];
          }
#pragma unroll
        for (int j = 0; j < CH; ++j)
          if (nb + CH + j < end) sN[j] = srcs[nb + CH + j];
      }
      compute(base, rB, eaB);
      base = nb;
      if (base >= end) break;
    }
  }

  float invd = 1.0f / fmaxf((float)(end - beg), 1.0f);
  es0 *= invd; es1 *= invd; es2 *= invd;
  float xls = xl[(size_t)n * 64 + lane];
  float m = xls + xrv + es0 * w.x + es1 * w.y + es2 * w.z;
  m = fmaxf(m, 0.2f * m);
  float v = m * w.w;
  v += __shfl_xor(v, 1);
  v += __shfl_xor(v, 2);
  v += __shfl_xor(v, 4);
  v += __shfl_xor(v, 8);
  v += __shfl_xor(v, 16);
  v += __shfl_xor(v, 32);
  float ex = __expf(v);
  den += ex;
  acc = fmaf(ex, xls, acc);

  float o = acc / den + bias[lane];
  o = o > 0.f ? o : __expf(o) - 1.0f;  // ELU
  out[(size_t)n * 64 + lane] = o;
}

// ---------------- graph boundaries (batch is sorted) ------------------------
__global__ void gbound_k(const int* __restrict__ batch, int* __restrict__ gstart,
                         int N, int G) {
  int g = blockIdx.x * 256 + threadIdx.x;
  if (g > G) return;
  int lo = 0, hi = N;
  while (lo < hi) {
    int mid = (lo + hi) >> 1;
    if (batch[mid] < g) lo = mid + 1;
    else hi = mid;
  }
  gstart[g] = lo;
}

// ---------------- fused mean-pool + MLP head (block per graph) --------------
__global__ void final_mlp_k(const float* __restrict__ h2, const int* __restrict__ gstart,
                            const float* __restrict__ u, const float* __restrict__ W1,
                            const float* __restrict__ b1, const float* __restrict__ Wh,
                            const float* __restrict__ bh, float* __restrict__ out) {
  __shared__ float feat[65];
  __shared__ float z[32];
  int g = blockIdx.x;
  int t = threadIdx.x;  // 64 threads
  int lo = gstart[g], hi = gstart[g + 1];
  float a = 0.f;
  for (int nn = lo; nn < hi; ++nn) a += h2[(size_t)nn * 64 + t];
  float inv = 1.0f / fmaxf((float)(hi - lo), 1.0f);
  feat[t] = a * inv;
  if (t == 0) feat[64] = u[g];
  __syncthreads();
  if (t < 32) {
    float s = b1[t];
    for (int k = 0; k < 65; ++k) s += feat[k] * W1[t * 65 + k];
    z[t] = fmaxf(s, 0.0f);
  }
  __syncthreads();
  if (t < 10) {
    float s = bh[t];
    for (int k = 0; k < 32; ++k) s += z[k] * Wh[t * 32 + k];
    out[g * 10 + t] = s;
  }
}

// ---------------------------------------------------------------------------
extern "C" void kernel_launch(void* const* d_in, const int* in_sizes, int n_in,
                              void* d_out, int out_size, void* d_ws, size_t ws_size,
                              hipStream_t stream) {
  const float* x      = (const float*)d_in[0];
  const int*   eidx   = (const int*)d_in[1];
  const float* eattr  = (const float*)d_in[2];
  const int*   batch  = (const int*)d_in[3];
  const float* u      = (const float*)d_in[4];
  const float* Wl1    = (const float*)d_in[5];
  const float* bl1    = (const float*)d_in[6];
  const float* Wr1    = (const float*)d_in[7];
  const float* br1    = (const float*)d_in[8];
  const float* We1    = (const float*)d_in[9];
  const float* att1   = (const float*)d_in[10];
  const float* b1     = (const float*)d_in[11];
  const float* Wl2    = (const float*)d_in[12];
  const float* bl2    = (const float*)d_in[13];
  const float* Wr2    = (const float*)d_in[14];
  const float* br2    = (const float*)d_in[15];
  const float* We2    = (const float*)d_in[16];
  const float* att2   = (const float*)d_in[17];
  const float* b2     = (const float*)d_in[18];
  const float* W_lin1 = (const float*)d_in[19];
  const float* b_lin1 = (const float*)d_in[20];
  const float* W_head = (const float*)d_in[21];
  const float* b_head = (const float*)d_in[22];

  const int N = in_sizes[0] / 128;
  const int E = in_sizes[1] / 2;
  const int G = in_sizes[4];
  const int* srcp = eidx;
  const int* dstp = eidx + E;

  // ---- workspace layout ----
  float* buf1 = (float*)d_ws;                       // xl1 (N*128) -> xl2 (N*64)
  float* buf2 = buf1 + (size_t)N * 128;             // xr1 (N*128) -> xr2 (N*64)
  float* buf3 = buf2 + (size_t)N * 128;             // h1  (N*128) -> h2  (N*64)
  float4* ea4 = (float4*)(buf3 + (size_t)N * 128);  // E sorted edge attrs
  int* srcs_s = (int*)(ea4 + E);                    // E sorted src ids
  int* deg    = srcs_s + E;                         // N
  int* rowptr = deg + N;                            // N+1
  int* cursor = rowptr + N + 1;                     // N
  int* bsum   = cursor + N;                         // 256
  int* gstart = bsum + 256;                         // G+1

  const int nb = (N + 255) / 256;

  // ---- CSR build (sort edges by dst) ----
  hipMemsetAsync(deg, 0, sizeof(int) * (size_t)N, stream);
  hist_k<<<(E + 255) / 256, 256, 0, stream>>>(dstp, deg, E);
  blocksum_k<<<nb, 256, 0, stream>>>(deg, bsum, N);
  scan_bsum_k<<<1, 256, 0, stream>>>(bsum, nb);
  writeptr_k<<<nb, 256, 0, stream>>>(deg, bsum, rowptr, cursor, N, E);
  fill_k<<<(E + 255) / 256, 256, 0, stream>>>(srcp, dstp, eattr, cursor, srcs_s, ea4, E);
  gbound_k<<<(G + 256) / 256, 256, 0, stream>>>(batch, gstart, N, G);

  // ---- layer 1 ----
  node_linear2t_k<128><<<(N + 31) / 32, 256, 0, stream>>>(x, Wl1, bl1, Wr1, br1,
                                                          buf1, buf2, N);
  gat1_fused_k<<<(N + 3) / 4, 256, 0, stream>>>(rowptr, srcs_s, ea4, buf1, buf2,
                                                We1, att1, b1, buf3, N);

  // ---- layer 2 ----
  node_linear2t_k<64><<<(N + 63) / 64, 256, 0, stream>>>(buf3, Wl2, bl2, Wr2, br2,
                                                         buf1, buf2, N);
  gat2_fused_k<<<(N + 3) / 4, 256, 0, stream>>>(rowptr, srcs_s, ea4, buf1, buf2,
                                                We2, att2, b2, buf3, N);

  // ---- fused pool + head ----
  final_mlp_k<<<G, 64, 0, stream>>>(buf3, gstart, u, W_lin1, b_lin1, W_head, b_head,
                                    (float*)d_out);
}